// Round 1
// baseline (3324.566 us; speedup 1.0000x reference)
//
#include <hip/hip_runtime.h>
#include <stdint.h>

#define B_ 2
#define S_ 2048
#define D_ 2048
#define V_ 32000
#define K_ 3
#define NROWS (B_*S_)        // 4096
#define BM 128
#define BN 128
#define BK 32
#define NT (V_/BN)           // 250
#define MT (NROWS/BM)        // 32
#define EPSF 1e-6f

using short8 = __attribute__((ext_vector_type(8))) short;
using f32x4  = __attribute__((ext_vector_type(4))) float;

__device__ __forceinline__ unsigned short f2bf(float f) {
  union { float f; unsigned u; } v; v.f = f;
  unsigned r = (v.u + 0x7fffu + ((v.u >> 16) & 1u)) >> 16;   // RNE
  return (unsigned short)r;
}
__device__ __forceinline__ float bf2f(unsigned short u) {
  union { unsigned u; float f; } v; v.u = ((unsigned)u) << 16;
  return v.f;
}

#define GLL16(g, l) __builtin_amdgcn_global_load_lds( \
    (const __attribute__((address_space(1))) void*)(g), \
    (__attribute__((address_space(3))) void*)(l), 16, 0, 0)

// ---------------- rmsnorm: h (fp32) -> xb (bf16), w_norm NOT applied (folded into weights)
__global__ __launch_bounds__(256) void k_rmsnorm(const float* __restrict__ h,
                                                 unsigned short* __restrict__ xb) {
  const int row = blockIdx.x;
  const int tid = threadIdx.x;
  const float* hr = h + (size_t)row * D_;
  float4 v0 = *(const float4*)(hr + tid * 8);
  float4 v1 = *(const float4*)(hr + tid * 8 + 4);
  float ss = v0.x*v0.x + v0.y*v0.y + v0.z*v0.z + v0.w*v0.w
           + v1.x*v1.x + v1.y*v1.y + v1.z*v1.z + v1.w*v1.w;
  #pragma unroll
  for (int m = 1; m < 64; m <<= 1) ss += __shfl_xor(ss, m);
  __shared__ float red[4];
  if ((tid & 63) == 0) red[tid >> 6] = ss;
  __syncthreads();
  float scale = rsqrtf((red[0]+red[1]+red[2]+red[3]) * (1.0f / D_) + EPSF);
  short8 o;
  o[0]=(short)f2bf(v0.x*scale); o[1]=(short)f2bf(v0.y*scale);
  o[2]=(short)f2bf(v0.z*scale); o[3]=(short)f2bf(v0.w*scale);
  o[4]=(short)f2bf(v1.x*scale); o[5]=(short)f2bf(v1.y*scale);
  o[6]=(short)f2bf(v1.z*scale); o[7]=(short)f2bf(v1.w*scale);
  *(short8*)(xb + (size_t)row * D_ + tid * 8) = o;
}

// ---------------- convert+fold: wb[d][v][k] = bf16(w_proj[d][v][k] * w_norm[d][k])
__global__ __launch_bounds__(256) void k_convw(const float* __restrict__ wp,
                                               const float* __restrict__ wn,
                                               unsigned short* __restrict__ wb) {
  const int d = blockIdx.y;
  const size_t e = ((size_t)blockIdx.x * 256 + threadIdx.x) * 4;  // within-d element
  const int k = (int)(e & (size_t)(D_ - 1));
  const size_t base = (size_t)d * V_ * D_;
  float4 w = *(const float4*)(wp + base + e);
  float4 n = *(const float4*)(wn + (size_t)d * D_ + k);
  ushort4 o;
  o.x = f2bf(w.x * n.x); o.y = f2bf(w.y * n.y);
  o.z = f2bf(w.z * n.z); o.w = f2bf(w.w * n.w);
  *(ushort4*)(wb + base + e) = o;
}

// ---------------- tiled GEMM + per-row tile-local (max, sumexp) partials
template<bool FAST>
__global__ __launch_bounds__(256) void k_gemm(const unsigned short* __restrict__ xb,
                                              const unsigned short* __restrict__ wb,
                                              const float* __restrict__ wp,
                                              const float* __restrict__ wn,
                                              float2* __restrict__ partials) {
  __shared__ __align__(16) unsigned short As[BM][BK];   // 8 KB
  __shared__ __align__(16) unsigned short Bs[BN][BK];   // 8 KB
  __shared__ float2 red[2][2][64];                      // 2 KB

  const int tid = threadIdx.x;
  const int d  = blockIdx.z;
  const int m0 = blockIdx.y * BM;
  const int v0 = blockIdx.x * BN;
  const int lane = tid & 63, wid = tid >> 6;
  const int wr = wid & 1, wc = wid >> 1;
  const int l15 = lane & 15, lk = lane >> 4;

  f32x4 acc[4][4] = {};

  for (int kt = 0; kt < D_ / BK; ++kt) {
    const int k0 = kt * BK;
    // stage A (xb): 128 rows x 32 k, linear-in-lane LDS dest
    #pragma unroll
    for (int i = 0; i < 2; ++i) {
      const int idx = i * 256 + tid;                 // 0..511, 16B each
      const unsigned short* ga = xb + (size_t)(m0 + (idx >> 2)) * D_ + k0 + (idx & 3) * 8;
      GLL16(ga, (unsigned short*)&As[0][0] + (size_t)idx * 8);
    }
    if (FAST) {
      #pragma unroll
      for (int i = 0; i < 2; ++i) {
        const int idx = i * 256 + tid;
        const unsigned short* gb = wb + ((size_t)d * V_ + v0 + (idx >> 2)) * D_ + k0 + (idx & 3) * 8;
        GLL16(gb, (unsigned short*)&Bs[0][0] + (size_t)idx * 8);
      }
    } else {
      #pragma unroll
      for (int i = 0; i < 4; ++i) {
        const int idx = i * 256 + tid;               // 0..1023
        const int r = idx >> 3, c = idx & 7;
        float4 w = *(const float4*)(wp + ((size_t)d * V_ + v0 + r) * D_ + k0 + c * 4);
        float4 n = *(const float4*)(wn + (size_t)d * D_ + k0 + c * 4);
        ushort4 o;
        o.x = f2bf(w.x * n.x); o.y = f2bf(w.y * n.y);
        o.z = f2bf(w.z * n.z); o.w = f2bf(w.w * n.w);
        *(ushort4*)(&Bs[r][c * 4]) = o;
      }
    }
    __syncthreads();

    short8 a[4], b[4];
    #pragma unroll
    for (int m = 0; m < 4; ++m) a[m] = *(const short8*)&As[wr * 64 + m * 16 + l15][lk * 8];
    #pragma unroll
    for (int n = 0; n < 4; ++n) b[n] = *(const short8*)&Bs[wc * 64 + n * 16 + l15][lk * 8];
    #pragma unroll
    for (int m = 0; m < 4; ++m)
      #pragma unroll
      for (int n = 0; n < 4; ++n)
        acc[m][n] = __builtin_amdgcn_mfma_f32_16x16x32_bf16(a[m], b[n], acc[m][n], 0, 0, 0);
    __syncthreads();
  }

  // per-row (max, sumexp) over this block's 128 columns
  // C/D layout: col = lane&15, row = (lane>>4)*4 + reg  (within 16x16 frag)
  #pragma unroll
  for (int m = 0; m < 4; ++m) {
    #pragma unroll
    for (int r = 0; r < 4; ++r) {
      float x0 = acc[m][0][r], x1 = acc[m][1][r], x2 = acc[m][2][r], x3 = acc[m][3][r];
      float mx = fmaxf(fmaxf(x0, x1), fmaxf(x2, x3));
      #pragma unroll
      for (int msk = 1; msk < 16; msk <<= 1) mx = fmaxf(mx, __shfl_xor(mx, msk));
      float sm = __expf(x0 - mx) + __expf(x1 - mx) + __expf(x2 - mx) + __expf(x3 - mx);
      #pragma unroll
      for (int msk = 1; msk < 16; msk <<= 1) sm += __shfl_xor(sm, msk);
      if (l15 == 0) red[wr][wc][m * 16 + lk * 4 + r] = make_float2(mx, sm);
    }
  }
  __syncthreads();
  if (tid < 128) {
    const int rw = tid >> 6, ri = tid & 63;
    float2 p0 = red[rw][0][ri], p1 = red[rw][1][ri];
    float M = fmaxf(p0.x, p1.x);
    float Ssum = p0.y * __expf(p0.x - M) + p1.y * __expf(p1.x - M);
    const int grow = m0 + tid;
    partials[((size_t)d * NROWS + grow) * NT + blockIdx.x] = make_float2(M, Ssum);
  }
}

// ---------------- per-row: combine partials -> lse; recompute target logit; accumulate loss
template<bool FAST>
__global__ __launch_bounds__(256) void k_loss(const unsigned short* __restrict__ xb,
                                              const unsigned short* __restrict__ wb,
                                              const float* __restrict__ wp,
                                              const float* __restrict__ wn,
                                              const float2* __restrict__ partials,
                                              const int* __restrict__ ids,
                                              float* __restrict__ out) {
  const int rix = blockIdx.x;            // 0 .. K_*NROWS-1
  const int d = rix >> 12;               // NROWS = 4096
  const int rowflat = rix & (NROWS - 1);
  const int b = rowflat >> 11, s = rowflat & (S_ - 1);
  const int shift = d + 1;
  if (s + shift >= S_) return;           // block-uniform
  const int tid = threadIdx.x;
  const int t = ids[b * S_ + s + shift];

  // dot(xb[row], wfold[d][t]) over D
  float part = 0.f;
  short8 xv = *(const short8*)(xb + (size_t)rowflat * D_ + tid * 8);
  if (FAST) {
    short8 wv = *(const short8*)(wb + ((size_t)d * V_ + t) * D_ + tid * 8);
    #pragma unroll
    for (int j = 0; j < 8; ++j) part += bf2f((unsigned short)xv[j]) * bf2f((unsigned short)wv[j]);
  } else {
    const float* wrow = wp + ((size_t)d * V_ + t) * D_ + tid * 8;
    const float* nrow = wn + (size_t)d * D_ + tid * 8;
    #pragma unroll
    for (int j = 0; j < 8; ++j) part += bf2f((unsigned short)xv[j]) * bf2f(f2bf(wrow[j] * nrow[j]));
  }
  #pragma unroll
  for (int msk = 1; msk < 64; msk <<= 1) part += __shfl_xor(part, msk);
  __shared__ float rsum[4], mred[4], sred[4];
  if ((tid & 63) == 0) rsum[tid >> 6] = part;
  __syncthreads();
  const float logit_t = rsum[0] + rsum[1] + rsum[2] + rsum[3];

  // logsumexp over NT partials
  float2 p = make_float2(-1e30f, 0.f);
  if (tid < NT) p = partials[((size_t)d * NROWS + rowflat) * NT + tid];
  float lm = p.x;
  #pragma unroll
  for (int msk = 1; msk < 64; msk <<= 1) lm = fmaxf(lm, __shfl_xor(lm, msk));
  if ((tid & 63) == 0) mred[tid >> 6] = lm;
  __syncthreads();
  const float M = fmaxf(fmaxf(mred[0], mred[1]), fmaxf(mred[2], mred[3]));
  float c = (tid < NT) ? p.y * __expf(p.x - M) : 0.f;
  #pragma unroll
  for (int msk = 1; msk < 64; msk <<= 1) c += __shfl_xor(c, msk);
  if ((tid & 63) == 0) sred[tid >> 6] = c;
  __syncthreads();
  if (tid == 0) {
    const float SM = sred[0] + sred[1] + sred[2] + sred[3];
    const float lse = M + logf(SM);
    const float nll = lse - logit_t;
    const float coef = 0.1f / (float)(B_ * (S_ - shift));  // 0.3/K * mean
    atomicAdd(out, coef * nll);
  }
}

extern "C" void kernel_launch(void* const* d_in, const int* in_sizes, int n_in,
                              void* d_out, int out_size, void* d_ws, size_t ws_size,
                              hipStream_t stream) {
  const float* h  = (const float*)d_in[0];
  const float* wn = (const float*)d_in[1];
  const float* wp = (const float*)d_in[2];
  const int*  ids = (const int*)d_in[3];
  float* out = (float*)d_out;

  char* ws = (char*)d_ws;
  size_t off = 0;
  unsigned short* xb = (unsigned short*)(ws + off);
  off += (size_t)NROWS * D_ * sizeof(unsigned short);          // 16,777,216
  float2* partials = (float2*)(ws + off);
  off += (size_t)K_ * NROWS * NT * sizeof(float2);             // 24,576,000
  unsigned short* wb = (unsigned short*)(ws + off);
  const size_t need_fast = off + (size_t)K_ * V_ * D_ * sizeof(unsigned short); // ~435 MB
  const bool fast = (ws_size >= need_fast);

  hipMemsetAsync(d_out, 0, sizeof(float), stream);
  k_rmsnorm<<<NROWS, 256, 0, stream>>>(h, xb);
  if (fast) {
    k_convw<<<dim3(V_ * D_ / 1024, K_), 256, 0, stream>>>(wp, wn, wb);
    k_gemm<true><<<dim3(NT, MT, K_), 256, 0, stream>>>(xb, wb, nullptr, nullptr, partials);
    k_loss<true><<<K_ * NROWS, 256, 0, stream>>>(xb, wb, nullptr, nullptr, partials, ids, out);
  } else {
    k_gemm<false><<<dim3(NT, MT, K_), 256, 0, stream>>>(xb, nullptr, wp, wn, partials);
    k_loss<false><<<K_ * NROWS, 256, 0, stream>>>(xb, nullptr, wp, wn, partials, ids, out);
  }
}